// Round 5
// baseline (164.230 us; speedup 1.0000x reference)
//
#include <hip/hip_runtime.h>

// MoE_52037823758984: out[i] = x[i] @ W_{route[i]}^T + b_{route[i]}
// N = 2,097,152 tokens, D = 10, all f32 (route int32).
//
// R11 = R10 with ONE change: the load-side LDS transpose is deleted.
//   Each lane loads its own 2 rows DIRECTLY from global (5x b128 at
//   stride 80B, lane-private, 16B-aligned), instead of coalesced loads ->
//   ds_write -> ds_read.
//   Why: theory ledger so far -- per-wave pipelining dead (R8/R9: buffers
//   cost occupancy 32->14 waves, net loss); nt-store L3 theory dead (R10:
//   FETCH/WRITE bit-identical nt vs plain). Remaining anomaly: 130MB
//   fabric traffic at only 2.5 TB/s with VALU 12%, conflicts 0, occ 52%
//   -- all pipes idle. The one serializer never removed: the load-side
//   transpose makes the whole 6KB load set a monolithic barrier (no FMA
//   until the LAST load lands + LDS round-trips). Direct per-lane loads
//   dissolve it: compiler interleaves FMAs under progressive vmcnt(4..0),
//   and two dependent LDS hops disappear from the critical path.
//   Strided-within-span READS have zero HBM amplification (all fetched
//   lines fully consumed across the wave's 5 instrs; FETCH_SIZE verifies).
//   STORES keep R10's proven-clean coalesced LDS-transpose path (R5:
//   strided stores DO amplify; loads can't).
// Unchanged proven pieces:
//   - coalesced plain stores 1KB/instr (R10: identical counters to nt).
//   - packed f32 math: (row0,row1) in float2 -> v_pk_fma_f32 (R5).
//   - 4096 blocks x 256thr, 512 rows/block; LDS 20KB (out-staging only).
//   - VGPR watch-item: must stay <64 (R8 lesson: 68 halves occupancy).

#define BLOCK 256
#define D 10
#define WAVE_ROWS 128              // rows per wave
#define F4_PER_WAVE 320            // 128*10/4
#define ROWS_PER_BLOCK 512         // 4 waves

typedef float f4 __attribute__((ext_vector_type(4)));
typedef float f2 __attribute__((ext_vector_type(2)));

__global__ __launch_bounds__(BLOCK) void moe_kernel(
    const float* __restrict__ x,
    const float* __restrict__ W1,
    const float* __restrict__ b1,
    const float* __restrict__ W2,
    const float* __restrict__ b2,
    const int*   __restrict__ route,
    float*       __restrict__ out,
    int n)
{
    __shared__ f4 lds[(BLOCK / 64) * F4_PER_WAVE];  // 20 KB (out-staging)

    const int lane = threadIdx.x & 63;
    const int wave = threadIdx.x >> 6;
    f4* __restrict__ wlds = lds + wave * F4_PER_WAVE;

    const long long rowbase =
        ((long long)blockIdx.x * (BLOCK / 64) + wave) * WAVE_ROWS;

    if (rowbase + WAVE_ROWS <= n) {
        // ---------- direct per-lane loads: rows 2L, 2L+1 ----------
        // 5x b128 at stride 80B; base 16B-aligned (rowbase*40B is
        // 20480-multiple, lane*80B is 16-multiple). Every byte of the
        // wave's 5KB span is consumed -> no fetch amplification.
        const f4* __restrict__ xv = (const f4*)(x + rowbase * D);
        const int2 rt = ((const int2*)(route + rowbase))[lane];

        float xf[2 * D];
        #pragma unroll
        for (int j = 0; j < 5; ++j) {
            f4 t = xv[lane * 5 + j];        // direct: no LDS round trip
            xf[4 * j + 0] = t.x; xf[4 * j + 1] = t.y;
            xf[4 * j + 2] = t.z; xf[4 * j + 3] = t.w;
        }

        // row-pair vectors: xp[k] = (row0[k], row1[k])
        f2 xp[D];
        #pragma unroll
        for (int k = 0; k < D; ++k)
            xp[k] = (f2){xf[k], xf[D + k]};

        // ---------- packed MLP: both experts, route-select ----------
        float o0[D], o1[D];
        #pragma unroll
        for (int j = 0; j < D; ++j) {
            f2 a0 = (f2){b1[j], b1[j]};
            f2 a1 = (f2){b2[j], b2[j]};
            #pragma unroll
            for (int k = 0; k < D; ++k) {
                const float w1 = W1[j * D + k];
                const float w2 = W2[j * D + k];
                a0 = __builtin_elementwise_fma(xp[k], (f2){w1, w1}, a0);
                a1 = __builtin_elementwise_fma(xp[k], (f2){w2, w2}, a1);
            }
            o0[j] = rt.x ? a1.x : a0.x;
            o1[j] = rt.y ? a1.y : a0.y;
        }

        // ---------- LDS transpose out (lane-private slots, in-order) ----
        {
            f4 t0 = (f4){o0[0], o0[1], o0[2], o0[3]};
            f4 t1 = (f4){o0[4], o0[5], o0[6], o0[7]};
            f4 t2 = (f4){o0[8], o0[9], o1[0], o1[1]};
            f4 t3 = (f4){o1[2], o1[3], o1[4], o1[5]};
            f4 t4 = (f4){o1[6], o1[7], o1[8], o1[9]};
            wlds[lane * 5 + 0] = t0;
            wlds[lane * 5 + 1] = t1;
            wlds[lane * 5 + 2] = t2;
            wlds[lane * 5 + 3] = t3;
            wlds[lane * 5 + 4] = t4;
        }
        __builtin_amdgcn_wave_barrier();  // order ds_write -> ds_read pair

        // ---------- coalesced plain stores (1 KB/instr, proven clean) ----
        f4* __restrict__ ov = (f4*)(out + rowbase * D);
        #pragma unroll
        for (int j = 0; j < 5; ++j)
            ov[j * 64 + lane] = wlds[j * 64 + lane];
    } else {
        // ---------- tail path (not hit for N=2097152) ----------
        for (int r = 0; r < 2; ++r) {
            const long long row = rowbase + lane * 2 + r;
            if (row < n) {
                const int sel = route[row];
                for (int j = 0; j < D; ++j) {
                    float y0 = b1[j];
                    float y1 = b2[j];
                    for (int k = 0; k < D; ++k) {
                        const float xk = x[row * D + k];
                        y0 = fmaf(xk, W1[j * D + k], y0);
                        y1 = fmaf(xk, W2[j * D + k], y1);
                    }
                    out[row * D + j] = sel ? y1 : y0;
                }
            }
        }
    }
}

extern "C" void kernel_launch(void* const* d_in, const int* in_sizes, int n_in,
                              void* d_out, int out_size, void* d_ws, size_t ws_size,
                              hipStream_t stream) {
    const float* x     = (const float*)d_in[0];
    const float* W1    = (const float*)d_in[1];
    const float* b1    = (const float*)d_in[2];
    const float* W2    = (const float*)d_in[3];
    const float* b2    = (const float*)d_in[4];
    const int*   route = (const int*)d_in[5];
    float*       out   = (float*)d_out;

    const int n = in_sizes[5];  // N tokens (route length)
    const int blocks = (n + ROWS_PER_BLOCK - 1) / ROWS_PER_BLOCK;  // 4096

    moe_kernel<<<blocks, BLOCK, 0, stream>>>(x, W1, b1, W2, b2, route, out, n);
}